// Round 16
// baseline (83.980 us; speedup 1.0000x reference)
//
#include <hip/hip_runtime.h>
#include <stdint.h>

#define EMB    1024
#define NHEAD  16
#define HDIM   64
#define NSEQ   2048
#define NBATCH 2
#define WINDOW 128
#define MROWS  (NBATCH * NSEQ)   // 4096

typedef __attribute__((ext_vector_type(8))) short  bf16x8;
typedef __attribute__((ext_vector_type(4))) float  f32x4;
typedef __attribute__((ext_vector_type(4))) short  short4v;

__device__ __forceinline__ unsigned short f2bf(float f) {
  union { float f; uint32_t u; } c; c.f = f;
  uint32_t u = c.u;
  u += 0x7fffu + ((u >> 16) & 1u);   // round-to-nearest-even
  return (unsigned short)(u >> 16);
}

#define GLOAD16(g, l) __builtin_amdgcn_global_load_lds( \
    (const __attribute__((address_space(1))) void*)(g), \
    (__attribute__((address_space(3))) void*)(l), 16, 0, 0)

// ---------------- fp32 -> bf16 convert (x + 4 weights, one launch) ----------------
__global__ __launch_bounds__(256) void cvt_all(
    const float* __restrict__ x,
    const float* __restrict__ w0, const float* __restrict__ w1,
    const float* __restrict__ w2, const float* __restrict__ w3,
    unsigned short* __restrict__ xb,
    unsigned short* __restrict__ o0, unsigned short* __restrict__ o1,
    unsigned short* __restrict__ o2, unsigned short* __restrict__ o3) {
  const int i = blockIdx.x * 256 + threadIdx.x;   // float4 index
  const float* src; unsigned short* dst; int off;
  if (i < 1048576) { src = x; dst = xb; off = i; }
  else {
    int j = i - 1048576;
    int sel = j >> 18; off = j & 262143;
    src = sel == 0 ? w0 : sel == 1 ? w1 : sel == 2 ? w2 : w3;
    dst = sel == 0 ? o0 : sel == 1 ? o1 : sel == 2 ? o2 : o3;
  }
  float4 v = ((const float4*)src)[off];
  short4v o;
  o.x = (short)f2bf(v.x);
  o.y = (short)f2bf(v.y);
  o.z = (short)f2bf(v.z);
  o.w = (short)f2bf(v.w);
  ((short4v*)dst)[off] = o;
}

// ---------------- pipelined GEMM: C[M,N] = A[M,K] * B[N,K]^T + bias ----------------
// BM=BN=128, BK=64, 2 LDS slots (64KB), 4 waves, counted-vmcnt pipeline,
// G4 row-XOR swizzle. (r11-verified form; r12-r15 variants all neutral/worse.)
// mode 0: bf16 out, plane-major [B][H][N][64]   (Q, K)
// mode 1: bf16 out, transposed  [B][H][64][N]   (V)  -- 8B packed stores
// mode 2: fp32 out, row-major [M][N]            (proj output)
__device__ __forceinline__ void gemm_pipe(const unsigned short* __restrict__ A,
                                          const unsigned short* __restrict__ Bw,
                                          const float* __restrict__ bias,
                                          void* __restrict__ Cv,
                                          int m0, int n0, int mode, float scale) {
  constexpr int K = 1024, BK = 64, NT = K / BK;   // 16 K-tiles
  __shared__ char lds[2][32768];                   // [slot][A:16KB | B:16KB]
  const int t    = threadIdx.x;
  const int lane = t & 63;
  const int wv   = t >> 6;
  const int lhi  = lane >> 4, llo = lane & 15;
  const int wr   = wv >> 1, wc = wv & 1;

  const unsigned short* gsrc[8];
  int ldsoff[8];
  #pragma unroll
  for (int li = 0; li < 8; ++li) {
    const int isB = li >= 4;
    const int c = (isB ? (li - 4) : li) * 4 + wv;
    const int P = c * 1024 + lane * 16;
    const int L = P ^ (((P >> 7) & 7) << 4);
    const int row = L >> 7, sl = (L >> 4) & 7;
    gsrc[li] = (isB ? Bw + (size_t)(n0 + row) * K : A + (size_t)(m0 + row) * K) + sl * 8;
    ldsoff[li] = isB * 16384 + c * 1024;
  }

  int aoff[2][4], boff[2][4];
  #pragma unroll
  for (int ks = 0; ks < 2; ++ks)
    #pragma unroll
    for (int f = 0; f < 4; ++f) {
      const int ar = wr * 64 + f * 16 + llo;
      aoff[ks][f] = (ar * 128 + ks * 64 + lhi * 16) ^ ((ar & 7) << 4);
      const int bc = wc * 64 + f * 16 + llo;
      boff[ks][f] = 16384 + ((bc * 128 + ks * 64 + lhi * 16) ^ ((bc & 7) << 4));
    }

  const f32x4 zero = {0.f, 0.f, 0.f, 0.f};
  f32x4 acc[4][4];
  #pragma unroll
  for (int i = 0; i < 4; ++i)
    #pragma unroll
    for (int j = 0; j < 4; ++j) acc[i][j] = zero;

  #pragma unroll
  for (int li = 0; li < 8; ++li) GLOAD16(gsrc[li], (char*)lds + ldsoff[li]);
  #pragma unroll
  for (int li = 0; li < 8; ++li) GLOAD16(gsrc[li] + BK, (char*)lds + 32768 + ldsoff[li]);

  for (int t0 = 0; t0 < NT; ++t0) {
    if (t0 + 1 < NT) asm volatile("s_waitcnt vmcnt(8)" ::: "memory");
    else             asm volatile("s_waitcnt vmcnt(0)" ::: "memory");
    asm volatile("s_barrier" ::: "memory");
    __builtin_amdgcn_sched_barrier(0);

    const char* base = (const char*)lds + (t0 & 1) * 32768;
    bf16x8 af[2][4], bg[2][4];
    #pragma unroll
    for (int ks = 0; ks < 2; ++ks)
      #pragma unroll
      for (int f = 0; f < 4; ++f) {
        af[ks][f] = *(const bf16x8*)(base + aoff[ks][f]);
        bg[ks][f] = *(const bf16x8*)(base + boff[ks][f]);
      }
    asm volatile("s_waitcnt lgkmcnt(0)" ::: "memory");
    asm volatile("s_barrier" ::: "memory");
    __builtin_amdgcn_sched_barrier(0);

    if (t0 + 2 < NT) {
      #pragma unroll
      for (int li = 0; li < 8; ++li)
        GLOAD16(gsrc[li] + (t0 + 2) * BK, (char*)lds + (t0 & 1) * 32768 + ldsoff[li]);
    }

    __builtin_amdgcn_s_setprio(1);
    #pragma unroll
    for (int ks = 0; ks < 2; ++ks)
      #pragma unroll
      for (int mf = 0; mf < 4; ++mf)
        #pragma unroll
        for (int nf = 0; nf < 4; ++nf)
          acc[mf][nf] = __builtin_amdgcn_mfma_f32_16x16x32_bf16(af[ks][mf], bg[ks][nf], acc[mf][nf], 0, 0, 0);
    __builtin_amdgcn_s_setprio(0);
  }

  const int wm = wr * 64, wn = wc * 64;
  #pragma unroll
  for (int mf = 0; mf < 4; ++mf) {
    #pragma unroll
    for (int nf = 0; nf < 4; ++nf) {
      const int col = n0 + wn + nf * 16 + llo;
      if (mode == 1) {
        const int row_base = m0 + wm + mf * 16 + lhi * 4;
        const int bb = row_base >> 11, n = row_base & 2047;
        const int hh = col >> 6, dd = col & 63;
        short4v o;
        #pragma unroll
        for (int r = 0; r < 4; ++r) o[r] = (short)f2bf((acc[mf][nf][r] + bias[col]) * scale);
        unsigned short* p = (unsigned short*)Cv +
            ((size_t)((bb * NHEAD + hh) * HDIM + dd)) * NSEQ + n;
        *(short4v*)p = o;
      } else {
        #pragma unroll
        for (int r = 0; r < 4; ++r) {
          const int row = m0 + wm + mf * 16 + lhi * 4 + r;
          const float v = (acc[mf][nf][r] + bias[col]) * scale;
          if (mode == 0) {
            const int bb = row >> 11, n = row & 2047;
            const int hh = col >> 6, dd = col & 63;
            ((unsigned short*)Cv)[((size_t)(bb * NHEAD + hh) * NSEQ + n) * HDIM + dd] = f2bf(v);
          } else {
            ((float*)Cv)[(size_t)row * EMB + col] = v;
          }
        }
      }
    }
  }
}

// qkv: 768 blocks = 8 XCDs x 96; bijective remap groups 4 A-panels (24 blocks
// each) per XCD -> per-XCD A working set 1MB (L2-resident) instead of 8MB.
__global__ __launch_bounds__(256, 2) void gemm_qkv(
    const unsigned short* __restrict__ A,
    const unsigned short* __restrict__ W0, const unsigned short* __restrict__ W1,
    const unsigned short* __restrict__ W2,
    const float* __restrict__ b0, const float* __restrict__ b1, const float* __restrict__ b2,
    unsigned short* __restrict__ O0, unsigned short* __restrict__ O1,
    unsigned short* __restrict__ O2) {
  const int orig = blockIdx.x + 32 * blockIdx.y + 256 * blockIdx.z;
  const int xcd = orig & 7, j = orig >> 3;           // j in [0,96)
  const int bx = xcd * 4 + j / 24;                   // 4 A-panels per XCD
  const int r  = j % 24;
  const int by = r / 3, bz = r % 3;
  const int m0 = bx * 128, n0 = by * 128;
  const unsigned short* W = (bz == 0) ? W0 : (bz == 1) ? W1 : W2;
  const float* bb         = (bz == 0) ? b0 : (bz == 1) ? b1 : b2;
  unsigned short* O       = (bz == 0) ? O0 : (bz == 1) ? O1 : O2;
  const int mode          = (bz == 2) ? 1 : 0;
  const float scale       = (bz == 0) ? 0.03125f : 1.0f;  // fold 1/sqrt(EMB) into Q
  gemm_pipe(A, W, bb, (void*)O, m0, n0, mode, scale);
}

// proj: 256 blocks = 8 XCDs x 32; 4 A-panels (8 blocks each) per XCD.
__global__ __launch_bounds__(256, 2) void gemm_proj(
    const unsigned short* __restrict__ A, const unsigned short* __restrict__ W,
    const float* __restrict__ bias, float* __restrict__ O) {
  const int orig = blockIdx.x + 32 * blockIdx.y;
  const int xcd = orig & 7, j = orig >> 3;           // j in [0,32)
  const int bx = xcd * 4 + j / 8;
  const int by = j % 8;
  gemm_pipe(A, W, bias, (void*)O, bx * 128, by * 128, 2, 1.0f);
}

// ---------------- windowed flash attention, 64-key LDS-staged pipeline ----------------
// (Round-11 verified version: 5 chunks of 64 keys, double-buffered LDS,
// counted vmcnt(4), 2 barriers/chunk, GEMM-proven swizzles.)
__global__ __launch_bounds__(256, 4) void attn_kernel(
    const unsigned short* __restrict__ Qh, const unsigned short* __restrict__ Kh,
    const unsigned short* __restrict__ Vt, unsigned short* __restrict__ AO) {
  constexpr int NCH = 5;
  __shared__ char kv[2][16384];              // [slot][K 8KB | V 8KB]
  __shared__ unsigned short Pb[4][1024];     // per-wave 16x64 P (swizzled), 8KB
  const int t = threadIdx.x;
  const int lane = t & 63, wv = t >> 6;
  const int lhi = lane >> 4, llo = lane & 15;

  const int linear = blockIdx.x + 32 * (blockIdx.y + 16 * blockIdx.z);
  const int xcd = linear & 7, pos = linear >> 3;
  const int plane = xcd * 4 + (pos >> 5);
  const int qblk = pos & 31;
  const int b = plane >> 4, h = plane & 15;
  const int q0b = qblk * 64;
  const int q0 = q0b + wv * 16;

  const size_t pbase = (size_t)plane * NSEQ * HDIM;

  bf16x8 aq0, aq1;
  {
    const unsigned short* qp = Qh + pbase + (size_t)(q0 + llo) * HDIM + 8 * lhi;
    aq0 = *(const bf16x8*)qp;
    aq1 = *(const bf16x8*)(qp + 32);
  }

  int srow[4], scol8[4];
  #pragma unroll
  for (int li = 0; li < 4; ++li) {
    const int P = (li & 1) * 4096 + t * 16;
    const int L = P ^ (((P >> 7) & 7) << 4);
    srow[li] = L >> 7;
    scol8[li] = ((L >> 4) & 7) * 8;
  }

  int koff[4];
  #pragma unroll
  for (int half = 0; half < 4; ++half) {
    const int row = half * 16 + llo;
    koff[half] = (row * 128 + lhi * 16) ^ ((row & 7) << 4);
  }
  int voff[4][2];
  #pragma unroll
  for (int fd = 0; fd < 4; ++fd) {
    const int row = fd * 16 + llo;
    #pragma unroll
    for (int ks = 0; ks < 2; ++ks)
      voff[fd][ks] = 8192 + ((row * 128 + ks * 64 + lhi * 16) ^ ((row & 7) << 4));
  }
  int paoff[2];
  #pragma unroll
  for (int ks = 0; ks < 2; ++ks)
    paoff[ks] = (llo * 128 + ks * 64 + lhi * 16) ^ ((llo & 7) << 4);
  char* pb = (char*)&Pb[wv][0];

  bf16x8 vones;
  #pragma unroll
  for (int j = 0; j < 8; ++j) vones[j] = (short)0x3F80;   // bf16 1.0

  const f32x4 zero = {0.f, 0.f, 0.f, 0.f};
  f32x4 accv[4];
  f32x4 s_acc = zero;
  #pragma unroll
  for (int i = 0; i < 4; ++i) accv[i] = zero;

  auto stage = [&](int ct, int slot) {
    const int kb = q0b - WINDOW + ct * 64;
    #pragma unroll
    for (int li = 0; li < 2; ++li) {
      int n = kb + srow[li];
      n = n < 0 ? 0 : (n > NSEQ - 1 ? NSEQ - 1 : n);
      GLOAD16(Kh + pbase + (size_t)n * HDIM + scol8[li],
              (char*)kv[slot] + (li & 1) * 4096 + t * 16);
    }
    #pragma unroll
    for (int li = 2; li < 4; ++li) {
      int c = kb + scol8[li];
      c = c < 0 ? 0 : (c > NSEQ - 8 ? NSEQ - 8 : c);
      GLOAD16(Vt + pbase + (size_t)srow[li] * NSEQ + c,
              (char*)kv[slot] + 8192 + (li & 1) * 4096 + t * 16);
    }
  };

  stage(0, 0);
  stage(1, 1);

  for (int ct = 0; ct < NCH; ++ct) {
    if (ct + 1 < NCH) asm volatile("s_waitcnt vmcnt(4)" ::: "memory");
    else              asm volatile("s_waitcnt vmcnt(0)" ::: "memory");
    asm volatile("s_barrier" ::: "memory");
    __builtin_amdgcn_sched_barrier(0);

    const char* sb = kv[ct & 1];
    const int kb = q0b - WINDOW + ct * 64;

    f32x4 e[4];
    #pragma unroll
    for (int half = 0; half < 4; ++half) {
      bf16x8 k0 = *(const bf16x8*)(sb + koff[half]);
      bf16x8 k1 = *(const bf16x8*)(sb + (koff[half] ^ 64));
      f32x4 z = zero;
      z = __builtin_amdgcn_mfma_f32_16x16x32_bf16(aq0, k0, z, 0, 0, 0);
      z = __builtin_amdgcn_mfma_f32_16x16x32_bf16(aq1, k1, z, 0, 0, 0);
      e[half] = z;
    }

    #pragma unroll
    for (int half = 0; half < 4; ++half) {
      const int key = kb + half * 16 + llo;
      #pragma unroll
      for (int r = 0; r < 4; ++r) {
        const int q = q0 + lhi * 4 + r;
        const int dlt = key - q;
        const bool valid = (key >= 0) && (key < NSEQ) && (dlt <= WINDOW) && (dlt >= -WINDOW);
        const float p = __expf(valid ? fminf(e[half][r], 40.f) : -1e30f);
        const int row = lhi * 4 + r, col = half * 16 + llo;
        *(unsigned short*)(pb + ((row * 128 + col * 2) ^ ((row & 7) << 4))) = f2bf(p);
      }
    }
    const bf16x8 pa0 = *(const bf16x8*)(pb + paoff[0]);
    const bf16x8 pa1 = *(const bf16x8*)(pb + paoff[1]);

    bf16x8 bv[4][2];
    #pragma unroll
    for (int fd = 0; fd < 4; ++fd) {
      bv[fd][0] = *(const bf16x8*)(sb + voff[fd][0]);
      bv[fd][1] = *(const bf16x8*)(sb + voff[fd][1]);
    }
    asm volatile("s_waitcnt lgkmcnt(0)" ::: "memory");
    __builtin_amdgcn_sched_barrier(0);
    asm volatile("s_barrier" ::: "memory");
    __builtin_amdgcn_sched_barrier(0);

    if (ct + 2 < NCH) stage(ct + 2, ct & 1);

    __builtin_amdgcn_s_setprio(1);
    s_acc = __builtin_amdgcn_mfma_f32_16x16x32_bf16(pa0, vones, s_acc, 0, 0, 0);
    s_acc = __builtin_amdgcn_mfma_f32_16x16x32_bf16(pa1, vones, s_acc, 0, 0, 0);
    #pragma unroll
    for (int fd = 0; fd < 4; ++fd) {
      accv[fd] = __builtin_amdgcn_mfma_f32_16x16x32_bf16(pa0, bv[fd][0], accv[fd], 0, 0, 0);
      accv[fd] = __builtin_amdgcn_mfma_f32_16x16x32_bf16(pa1, bv[fd][1], accv[fd], 0, 0, 0);
    }
    __builtin_amdgcn_s_setprio(0);
  }

  #pragma unroll
  for (int fd = 0; fd < 4; ++fd) {
    #pragma unroll
    for (int r = 0; r < 4; ++r) {
      const float o = accv[fd][r] / s_acc[r];
      const int q = q0 + lhi * 4 + r;
      AO[((size_t)b * NSEQ + q) * EMB + h * HDIM + fd * 16 + llo] = f2bf(o);
    }
  }
}

// ---------------- launcher ----------------
extern "C" void kernel_launch(void* const* d_in, const int* in_sizes, int n_in,
                              void* d_out, int out_size, void* d_ws, size_t ws_size,
                              hipStream_t stream) {
  (void)in_sizes; (void)n_in; (void)out_size; (void)ws_size;
  const float* x  = (const float*)d_in[0];
  const float* Wq = (const float*)d_in[1];
  const float* bq = (const float*)d_in[2];
  const float* Wk = (const float*)d_in[3];
  const float* bk = (const float*)d_in[4];
  const float* Wv = (const float*)d_in[5];
  const float* bv = (const float*)d_in[6];
  const float* Wp = (const float*)d_in[7];
  const float* bp = (const float*)d_in[8];
  float* out = (float*)d_out;
  char* ws = (char*)d_ws;
  const size_t MB = 1u << 20;
  unsigned short* xb  = (unsigned short*)(ws + 0 * MB);
  unsigned short* Wqb = (unsigned short*)(ws + 8 * MB);
  unsigned short* Wkb = (unsigned short*)(ws + 10 * MB);
  unsigned short* Wvb = (unsigned short*)(ws + 12 * MB);
  unsigned short* Wpb = (unsigned short*)(ws + 14 * MB);
  unsigned short* Qb  = (unsigned short*)(ws + 16 * MB);
  unsigned short* Kb  = (unsigned short*)(ws + 24 * MB);
  unsigned short* Vtb = (unsigned short*)(ws + 32 * MB);
  unsigned short* AOb = (unsigned short*)(ws + 40 * MB);

  cvt_all<<<dim3(8192), dim3(256), 0, stream>>>(x, Wq, Wk, Wv, Wp,
                                                xb, Wqb, Wkb, Wvb, Wpb);

  gemm_qkv<<<dim3(MROWS / 128, EMB / 128, 3), dim3(256), 0, stream>>>(
      xb, Wqb, Wkb, Wvb, bq, bk, bv, Qb, Kb, Vtb);

  attn_kernel<<<dim3(NSEQ / 64, NHEAD, NBATCH), dim3(256), 0, stream>>>(Qb, Kb, Vtb, AOb);

  gemm_proj<<<dim3(MROWS / 128, EMB / 128), dim3(256), 0, stream>>>(AOb, Wpb, bp, out);
}

// Round 17
// 82.310 us; speedup vs baseline: 1.0203x; 1.0203x over previous
//
#include <hip/hip_runtime.h>
#include <stdint.h>

#define EMB    1024
#define NHEAD  16
#define HDIM   64
#define NSEQ   2048
#define NBATCH 2
#define WINDOW 128
#define MROWS  (NBATCH * NSEQ)   // 4096

typedef __attribute__((ext_vector_type(8))) short  bf16x8;
typedef __attribute__((ext_vector_type(4))) float  f32x4;
typedef __attribute__((ext_vector_type(4))) short  short4v;

__device__ __forceinline__ unsigned short f2bf(float f) {
  union { float f; uint32_t u; } c; c.f = f;
  uint32_t u = c.u;
  u += 0x7fffu + ((u >> 16) & 1u);   // round-to-nearest-even
  return (unsigned short)(u >> 16);
}

#define GLOAD16(g, l) __builtin_amdgcn_global_load_lds( \
    (const __attribute__((address_space(1))) void*)(g), \
    (__attribute__((address_space(3))) void*)(l), 16, 0, 0)

// ---------------- fp32 -> bf16 convert (x + 4 weights, one launch) ----------------
__global__ __launch_bounds__(256) void cvt_all(
    const float* __restrict__ x,
    const float* __restrict__ w0, const float* __restrict__ w1,
    const float* __restrict__ w2, const float* __restrict__ w3,
    unsigned short* __restrict__ xb,
    unsigned short* __restrict__ o0, unsigned short* __restrict__ o1,
    unsigned short* __restrict__ o2, unsigned short* __restrict__ o3) {
  const int i = blockIdx.x * 256 + threadIdx.x;   // float4 index
  const float* src; unsigned short* dst; int off;
  if (i < 1048576) { src = x; dst = xb; off = i; }
  else {
    int j = i - 1048576;
    int sel = j >> 18; off = j & 262143;
    src = sel == 0 ? w0 : sel == 1 ? w1 : sel == 2 ? w2 : w3;
    dst = sel == 0 ? o0 : sel == 1 ? o1 : sel == 2 ? o2 : o3;
  }
  float4 v = ((const float4*)src)[off];
  short4v o;
  o.x = (short)f2bf(v.x);
  o.y = (short)f2bf(v.y);
  o.z = (short)f2bf(v.z);
  o.w = (short)f2bf(v.w);
  ((short4v*)dst)[off] = o;
}

// ---------------- pipelined GEMM: C[M,N] = A[M,K] * B[N,K]^T + bias ----------------
// r17: BK=32, 2 LDS slots of 16KB (32KB total -> 5 blocks/CU, full 768-block
// residency; m97-verified geometry). Same 2-barrier counted-vmcnt skeleton as
// the r11-verified BK=64 form. 64B rows carry 2 swizzle bits:
//   stage:  P = c*1024+lane*16, L = P ^ (((P>>6)&3)<<4)  (inverse-swz source)
//   read:   P = (row*64 + lhi*16) ^ ((row&3)<<4)         (residual 4-way, ~1.58x)
// vmcnt(4) steady (4 loads/tile, staged 2 tiles ahead).
// mode 0: bf16 out, plane-major [B][H][N][64]   (Q, K)
// mode 1: bf16 out, transposed  [B][H][64][N]   (V)  -- 8B packed stores
// mode 2: fp32 out, row-major [M][N]            (proj output)
__device__ __forceinline__ void gemm_pipe(const unsigned short* __restrict__ A,
                                          const unsigned short* __restrict__ Bw,
                                          const float* __restrict__ bias,
                                          void* __restrict__ Cv,
                                          int m0, int n0, int mode, float scale) {
  constexpr int K = 1024, BK = 32, NT = K / BK;   // 32 K-tiles
  __shared__ char lds[2][16384];                   // [slot][A:8KB | B:8KB]
  const int t    = threadIdx.x;
  const int lane = t & 63;
  const int wv   = t >> 6;
  const int lhi  = lane >> 4, llo = lane & 15;
  const int wr   = wv >> 1, wc = wv & 1;

  // staging: 4 gloads/thread/tile (2 A + 2 B)
  const unsigned short* gsrc[4];
  int ldsoff[4];
  #pragma unroll
  for (int li = 0; li < 4; ++li) {
    const int isB = li >= 2;
    const int c = (li & 1) * 4 + wv;               // chunk 0..7 within 8KB region
    const int P = c * 1024 + lane * 16;
    const int L = P ^ (((P >> 6) & 3) << 4);
    const int row = L >> 6, sl = (L >> 4) & 3;     // row 0..127, 8-elem slot 0..3
    gsrc[li] = (isB ? Bw + (size_t)(n0 + row) * K : A + (size_t)(m0 + row) * K) + sl * 8;
    ldsoff[li] = isB * 8192 + c * 1024;            // wave-uniform
  }

  int aoff[4], boff[4];
  #pragma unroll
  for (int f = 0; f < 4; ++f) {
    const int ar = wr * 64 + f * 16 + llo;
    aoff[f] = (ar * 64 + lhi * 16) ^ ((ar & 3) << 4);
    const int bc = wc * 64 + f * 16 + llo;
    boff[f] = 8192 + ((bc * 64 + lhi * 16) ^ ((bc & 3) << 4));
  }

  const f32x4 zero = {0.f, 0.f, 0.f, 0.f};
  f32x4 acc[4][4];
  #pragma unroll
  for (int i = 0; i < 4; ++i)
    #pragma unroll
    for (int j = 0; j < 4; ++j) acc[i][j] = zero;

  // prologue: stage tiles 0 and 1
  #pragma unroll
  for (int li = 0; li < 4; ++li) GLOAD16(gsrc[li], (char*)lds + ldsoff[li]);
  #pragma unroll
  for (int li = 0; li < 4; ++li) GLOAD16(gsrc[li] + BK, (char*)lds + 16384 + ldsoff[li]);

  for (int t0 = 0; t0 < NT; ++t0) {
    if (t0 + 1 < NT) asm volatile("s_waitcnt vmcnt(4)" ::: "memory");
    else             asm volatile("s_waitcnt vmcnt(0)" ::: "memory");
    asm volatile("s_barrier" ::: "memory");
    __builtin_amdgcn_sched_barrier(0);

    const char* base = (const char*)lds + (t0 & 1) * 16384;
    bf16x8 af[4], bg[4];
    #pragma unroll
    for (int f = 0; f < 4; ++f) {
      af[f] = *(const bf16x8*)(base + aoff[f]);
      bg[f] = *(const bf16x8*)(base + boff[f]);
    }
    asm volatile("s_waitcnt lgkmcnt(0)" ::: "memory");
    asm volatile("s_barrier" ::: "memory");
    __builtin_amdgcn_sched_barrier(0);

    if (t0 + 2 < NT) {
      #pragma unroll
      for (int li = 0; li < 4; ++li)
        GLOAD16(gsrc[li] + (t0 + 2) * BK, (char*)lds + (t0 & 1) * 16384 + ldsoff[li]);
    }

    __builtin_amdgcn_s_setprio(1);
    #pragma unroll
    for (int mf = 0; mf < 4; ++mf)
      #pragma unroll
      for (int nf = 0; nf < 4; ++nf)
        acc[mf][nf] = __builtin_amdgcn_mfma_f32_16x16x32_bf16(af[mf], bg[nf], acc[mf][nf], 0, 0, 0);
    __builtin_amdgcn_s_setprio(0);
  }

  const int wm = wr * 64, wn = wc * 64;
  #pragma unroll
  for (int mf = 0; mf < 4; ++mf) {
    #pragma unroll
    for (int nf = 0; nf < 4; ++nf) {
      const int col = n0 + wn + nf * 16 + llo;
      if (mode == 1) {
        const int row_base = m0 + wm + mf * 16 + lhi * 4;
        const int bb = row_base >> 11, n = row_base & 2047;
        const int hh = col >> 6, dd = col & 63;
        short4v o;
        #pragma unroll
        for (int r = 0; r < 4; ++r) o[r] = (short)f2bf((acc[mf][nf][r] + bias[col]) * scale);
        unsigned short* p = (unsigned short*)Cv +
            ((size_t)((bb * NHEAD + hh) * HDIM + dd)) * NSEQ + n;
        *(short4v*)p = o;
      } else {
        #pragma unroll
        for (int r = 0; r < 4; ++r) {
          const int row = m0 + wm + mf * 16 + lhi * 4 + r;
          const float v = (acc[mf][nf][r] + bias[col]) * scale;
          if (mode == 0) {
            const int bb = row >> 11, n = row & 2047;
            const int hh = col >> 6, dd = col & 63;
            ((unsigned short*)Cv)[((size_t)(bb * NHEAD + hh) * NSEQ + n) * HDIM + dd] = f2bf(v);
          } else {
            ((float*)Cv)[(size_t)row * EMB + col] = v;
          }
        }
      }
    }
  }
}

__global__ __launch_bounds__(256, 2) void gemm_qkv(
    const unsigned short* __restrict__ A,
    const unsigned short* __restrict__ W0, const unsigned short* __restrict__ W1,
    const unsigned short* __restrict__ W2,
    const float* __restrict__ b0, const float* __restrict__ b1, const float* __restrict__ b2,
    unsigned short* __restrict__ O0, unsigned short* __restrict__ O1,
    unsigned short* __restrict__ O2) {
  const int m0 = blockIdx.x * 128, n0 = blockIdx.y * 128;
  const unsigned short* W = (blockIdx.z == 0) ? W0 : (blockIdx.z == 1) ? W1 : W2;
  const float* bb         = (blockIdx.z == 0) ? b0 : (blockIdx.z == 1) ? b1 : b2;
  unsigned short* O       = (blockIdx.z == 0) ? O0 : (blockIdx.z == 1) ? O1 : O2;
  const int mode          = (blockIdx.z == 2) ? 1 : 0;
  const float scale       = (blockIdx.z == 0) ? 0.03125f : 1.0f;  // fold 1/sqrt(EMB) into Q
  gemm_pipe(A, W, bb, (void*)O, m0, n0, mode, scale);
}

__global__ __launch_bounds__(256, 2) void gemm_proj(
    const unsigned short* __restrict__ A, const unsigned short* __restrict__ W,
    const float* __restrict__ bias, float* __restrict__ O) {
  gemm_pipe(A, W, bias, (void*)O, blockIdx.x * 128, blockIdx.y * 128, 2, 1.0f);
}

// ---------------- windowed flash attention, 64-key LDS-staged pipeline ----------------
// (Round-11 verified version: 5 chunks of 64 keys, double-buffered LDS,
// counted vmcnt(4), 2 barriers/chunk, GEMM-proven swizzles.)
__global__ __launch_bounds__(256, 4) void attn_kernel(
    const unsigned short* __restrict__ Qh, const unsigned short* __restrict__ Kh,
    const unsigned short* __restrict__ Vt, unsigned short* __restrict__ AO) {
  constexpr int NCH = 5;
  __shared__ char kv[2][16384];              // [slot][K 8KB | V 8KB]
  __shared__ unsigned short Pb[4][1024];     // per-wave 16x64 P (swizzled), 8KB
  const int t = threadIdx.x;
  const int lane = t & 63, wv = t >> 6;
  const int lhi = lane >> 4, llo = lane & 15;

  const int linear = blockIdx.x + 32 * (blockIdx.y + 16 * blockIdx.z);
  const int xcd = linear & 7, pos = linear >> 3;
  const int plane = xcd * 4 + (pos >> 5);
  const int qblk = pos & 31;
  const int b = plane >> 4, h = plane & 15;
  const int q0b = qblk * 64;
  const int q0 = q0b + wv * 16;

  const size_t pbase = (size_t)plane * NSEQ * HDIM;

  bf16x8 aq0, aq1;
  {
    const unsigned short* qp = Qh + pbase + (size_t)(q0 + llo) * HDIM + 8 * lhi;
    aq0 = *(const bf16x8*)qp;
    aq1 = *(const bf16x8*)(qp + 32);
  }

  int srow[4], scol8[4];
  #pragma unroll
  for (int li = 0; li < 4; ++li) {
    const int P = (li & 1) * 4096 + t * 16;
    const int L = P ^ (((P >> 7) & 7) << 4);
    srow[li] = L >> 7;
    scol8[li] = ((L >> 4) & 7) * 8;
  }

  int koff[4];
  #pragma unroll
  for (int half = 0; half < 4; ++half) {
    const int row = half * 16 + llo;
    koff[half] = (row * 128 + lhi * 16) ^ ((row & 7) << 4);
  }
  int voff[4][2];
  #pragma unroll
  for (int fd = 0; fd < 4; ++fd) {
    const int row = fd * 16 + llo;
    #pragma unroll
    for (int ks = 0; ks < 2; ++ks)
      voff[fd][ks] = 8192 + ((row * 128 + ks * 64 + lhi * 16) ^ ((row & 7) << 4));
  }
  int paoff[2];
  #pragma unroll
  for (int ks = 0; ks < 2; ++ks)
    paoff[ks] = (llo * 128 + ks * 64 + lhi * 16) ^ ((llo & 7) << 4);
  char* pb = (char*)&Pb[wv][0];

  bf16x8 vones;
  #pragma unroll
  for (int j = 0; j < 8; ++j) vones[j] = (short)0x3F80;   // bf16 1.0

  const f32x4 zero = {0.f, 0.f, 0.f, 0.f};
  f32x4 accv[4];
  f32x4 s_acc = zero;
  #pragma unroll
  for (int i = 0; i < 4; ++i) accv[i] = zero;

  auto stage = [&](int ct, int slot) {
    const int kb = q0b - WINDOW + ct * 64;
    #pragma unroll
    for (int li = 0; li < 2; ++li) {
      int n = kb + srow[li];
      n = n < 0 ? 0 : (n > NSEQ - 1 ? NSEQ - 1 : n);
      GLOAD16(Kh + pbase + (size_t)n * HDIM + scol8[li],
              (char*)kv[slot] + (li & 1) * 4096 + t * 16);
    }
    #pragma unroll
    for (int li = 2; li < 4; ++li) {
      int c = kb + scol8[li];
      c = c < 0 ? 0 : (c > NSEQ - 8 ? NSEQ - 8 : c);
      GLOAD16(Vt + pbase + (size_t)srow[li] * NSEQ + c,
              (char*)kv[slot] + 8192 + (li & 1) * 4096 + t * 16);
    }
  };

  stage(0, 0);
  stage(1, 1);

  for (int ct = 0; ct < NCH; ++ct) {
    if (ct + 1 < NCH) asm volatile("s_waitcnt vmcnt(4)" ::: "memory");
    else              asm volatile("s_waitcnt vmcnt(0)" ::: "memory");
    asm volatile("s_barrier" ::: "memory");
    __builtin_amdgcn_sched_barrier(0);

    const char* sb = kv[ct & 1];
    const int kb = q0b - WINDOW + ct * 64;

    f32x4 e[4];
    #pragma unroll
    for (int half = 0; half < 4; ++half) {
      bf16x8 k0 = *(const bf16x8*)(sb + koff[half]);
      bf16x8 k1 = *(const bf16x8*)(sb + (koff[half] ^ 64));
      f32x4 z = zero;
      z = __builtin_amdgcn_mfma_f32_16x16x32_bf16(aq0, k0, z, 0, 0, 0);
      z = __builtin_amdgcn_mfma_f32_16x16x32_bf16(aq1, k1, z, 0, 0, 0);
      e[half] = z;
    }

    #pragma unroll
    for (int half = 0; half < 4; ++half) {
      const int key = kb + half * 16 + llo;
      #pragma unroll
      for (int r = 0; r < 4; ++r) {
        const int q = q0 + lhi * 4 + r;
        const int dlt = key - q;
        const bool valid = (key >= 0) && (key < NSEQ) && (dlt <= WINDOW) && (dlt >= -WINDOW);
        const float p = __expf(valid ? fminf(e[half][r], 40.f) : -1e30f);
        const int row = lhi * 4 + r, col = half * 16 + llo;
        *(unsigned short*)(pb + ((row * 128 + col * 2) ^ ((row & 7) << 4))) = f2bf(p);
      }
    }
    const bf16x8 pa0 = *(const bf16x8*)(pb + paoff[0]);
    const bf16x8 pa1 = *(const bf16x8*)(pb + paoff[1]);

    bf16x8 bv[4][2];
    #pragma unroll
    for (int fd = 0; fd < 4; ++fd) {
      bv[fd][0] = *(const bf16x8*)(sb + voff[fd][0]);
      bv[fd][1] = *(const bf16x8*)(sb + voff[fd][1]);
    }
    asm volatile("s_waitcnt lgkmcnt(0)" ::: "memory");
    __builtin_amdgcn_sched_barrier(0);
    asm volatile("s_barrier" ::: "memory");
    __builtin_amdgcn_sched_barrier(0);

    if (ct + 2 < NCH) stage(ct + 2, ct & 1);

    __builtin_amdgcn_s_setprio(1);
    s_acc = __builtin_amdgcn_mfma_f32_16x16x32_bf16(pa0, vones, s_acc, 0, 0, 0);
    s_acc = __builtin_amdgcn_mfma_f32_16x16x32_bf16(pa1, vones, s_acc, 0, 0, 0);
    #pragma unroll
    for (int fd = 0; fd < 4; ++fd) {
      accv[fd] = __builtin_amdgcn_mfma_f32_16x16x32_bf16(pa0, bv[fd][0], accv[fd], 0, 0, 0);
      accv[fd] = __builtin_amdgcn_mfma_f32_16x16x32_bf16(pa1, bv[fd][1], accv[fd], 0, 0, 0);
    }
    __builtin_amdgcn_s_setprio(0);
  }

  #pragma unroll
  for (int fd = 0; fd < 4; ++fd) {
    #pragma unroll
    for (int r = 0; r < 4; ++r) {
      const float o = accv[fd][r] / s_acc[r];
      const int q = q0 + lhi * 4 + r;
      AO[((size_t)b * NSEQ + q) * EMB + h * HDIM + fd * 16 + llo] = f2bf(o);
    }
  }
}

// ---------------- launcher ----------------
extern "C" void kernel_launch(void* const* d_in, const int* in_sizes, int n_in,
                              void* d_out, int out_size, void* d_ws, size_t ws_size,
                              hipStream_t stream) {
  (void)in_sizes; (void)n_in; (void)out_size; (void)ws_size;
  const float* x  = (const float*)d_in[0];
  const float* Wq = (const float*)d_in[1];
  const float* bq = (const float*)d_in[2];
  const float* Wk = (const float*)d_in[3];
  const float* bk = (const float*)d_in[4];
  const float* Wv = (const float*)d_in[5];
  const float* bv = (const float*)d_in[6];
  const float* Wp = (const float*)d_in[7];
  const float* bp = (const float*)d_in[8];
  float* out = (float*)d_out;
  char* ws = (char*)d_ws;
  const size_t MB = 1u << 20;
  unsigned short* xb  = (unsigned short*)(ws + 0 * MB);
  unsigned short* Wqb = (unsigned short*)(ws + 8 * MB);
  unsigned short* Wkb = (unsigned short*)(ws + 10 * MB);
  unsigned short* Wvb = (unsigned short*)(ws + 12 * MB);
  unsigned short* Wpb = (unsigned short*)(ws + 14 * MB);
  unsigned short* Qb  = (unsigned short*)(ws + 16 * MB);
  unsigned short* Kb  = (unsigned short*)(ws + 24 * MB);
  unsigned short* Vtb = (unsigned short*)(ws + 32 * MB);
  unsigned short* AOb = (unsigned short*)(ws + 40 * MB);

  cvt_all<<<dim3(8192), dim3(256), 0, stream>>>(x, Wq, Wk, Wv, Wp,
                                                xb, Wqb, Wkb, Wvb, Wpb);

  gemm_qkv<<<dim3(MROWS / 128, EMB / 128, 3), dim3(256), 0, stream>>>(
      xb, Wqb, Wkb, Wvb, bq, bk, bv, Qb, Kb, Vtb);

  attn_kernel<<<dim3(NSEQ / 64, NHEAD, NBATCH), dim3(256), 0, stream>>>(Qb, Kb, Vtb, AOb);

  gemm_proj<<<dim3(MROWS / 128, EMB / 128), dim3(256), 0, stream>>>(AOb, Wpb, bp, out);
}

// Round 18
// 78.509 us; speedup vs baseline: 1.0697x; 1.0484x over previous
//
#include <hip/hip_runtime.h>
#include <stdint.h>

#define EMB    1024
#define NHEAD  16
#define HDIM   64
#define NSEQ   2048
#define NBATCH 2
#define WINDOW 128
#define MROWS  (NBATCH * NSEQ)   // 4096

typedef __attribute__((ext_vector_type(8))) short  bf16x8;
typedef __attribute__((ext_vector_type(4))) float  f32x4;
typedef __attribute__((ext_vector_type(4))) short  short4v;

__device__ __forceinline__ unsigned short f2bf(float f) {
  union { float f; uint32_t u; } c; c.f = f;
  uint32_t u = c.u;
  u += 0x7fffu + ((u >> 16) & 1u);   // round-to-nearest-even
  return (unsigned short)(u >> 16);
}

#define GLOAD16(g, l) __builtin_amdgcn_global_load_lds( \
    (const __attribute__((address_space(1))) void*)(g), \
    (__attribute__((address_space(3))) void*)(l), 16, 0, 0)

// ---------------- fp32 -> bf16 convert (x + 4 weights, one launch) ----------------
__global__ __launch_bounds__(256) void cvt_all(
    const float* __restrict__ x,
    const float* __restrict__ w0, const float* __restrict__ w1,
    const float* __restrict__ w2, const float* __restrict__ w3,
    unsigned short* __restrict__ xb,
    unsigned short* __restrict__ o0, unsigned short* __restrict__ o1,
    unsigned short* __restrict__ o2, unsigned short* __restrict__ o3) {
  const int i = blockIdx.x * 256 + threadIdx.x;   // float4 index
  const float* src; unsigned short* dst; int off;
  if (i < 1048576) { src = x; dst = xb; off = i; }
  else {
    int j = i - 1048576;
    int sel = j >> 18; off = j & 262143;
    src = sel == 0 ? w0 : sel == 1 ? w1 : sel == 2 ? w2 : w3;
    dst = sel == 0 ? o0 : sel == 1 ? o1 : sel == 2 ? o2 : o3;
  }
  float4 v = ((const float4*)src)[off];
  short4v o;
  o.x = (short)f2bf(v.x);
  o.y = (short)f2bf(v.y);
  o.z = (short)f2bf(v.z);
  o.w = (short)f2bf(v.w);
  ((short4v*)dst)[off] = o;
}

// ---------------- pipelined GEMM: C[M,N] = A[M,K] * B[N,K]^T + bias ----------------
// BM=BN=128, BK=64, 2 LDS slots (64KB total), 4 waves, counted-vmcnt pipeline,
// G4 row-XOR swizzle. (r11-verified 79.08us configuration; r12-r17 variants
// -- 256^2 2ph, split-lgkm, 32x32 MFMA, 4-phase schedules, XCD swizzle, BK=32
// -- all neutral-to-negative. This is the structure's local optimum at this
// problem geometry.)
// mode 0: bf16 out, plane-major [B][H][N][64]   (Q, K)
// mode 1: bf16 out, transposed  [B][H][64][N]   (V)  -- 8B packed stores
// mode 2: fp32 out, row-major [M][N]            (proj output)
__device__ __forceinline__ void gemm_pipe(const unsigned short* __restrict__ A,
                                          const unsigned short* __restrict__ Bw,
                                          const float* __restrict__ bias,
                                          void* __restrict__ Cv,
                                          int m0, int n0, int mode, float scale) {
  constexpr int K = 1024, BK = 64, NT = K / BK;   // 16 K-tiles
  __shared__ char lds[2][32768];                   // [slot][A:16KB | B:16KB]
  const int t    = threadIdx.x;
  const int lane = t & 63;
  const int wv   = t >> 6;
  const int lhi  = lane >> 4, llo = lane & 15;
  const int wr   = wv >> 1, wc = wv & 1;

  const unsigned short* gsrc[8];
  int ldsoff[8];
  #pragma unroll
  for (int li = 0; li < 8; ++li) {
    const int isB = li >= 4;
    const int c = (isB ? (li - 4) : li) * 4 + wv;
    const int P = c * 1024 + lane * 16;
    const int L = P ^ (((P >> 7) & 7) << 4);
    const int row = L >> 7, sl = (L >> 4) & 7;
    gsrc[li] = (isB ? Bw + (size_t)(n0 + row) * K : A + (size_t)(m0 + row) * K) + sl * 8;
    ldsoff[li] = isB * 16384 + c * 1024;
  }

  int aoff[2][4], boff[2][4];
  #pragma unroll
  for (int ks = 0; ks < 2; ++ks)
    #pragma unroll
    for (int f = 0; f < 4; ++f) {
      const int ar = wr * 64 + f * 16 + llo;
      aoff[ks][f] = (ar * 128 + ks * 64 + lhi * 16) ^ ((ar & 7) << 4);
      const int bc = wc * 64 + f * 16 + llo;
      boff[ks][f] = 16384 + ((bc * 128 + ks * 64 + lhi * 16) ^ ((bc & 7) << 4));
    }

  const f32x4 zero = {0.f, 0.f, 0.f, 0.f};
  f32x4 acc[4][4];
  #pragma unroll
  for (int i = 0; i < 4; ++i)
    #pragma unroll
    for (int j = 0; j < 4; ++j) acc[i][j] = zero;

  #pragma unroll
  for (int li = 0; li < 8; ++li) GLOAD16(gsrc[li], (char*)lds + ldsoff[li]);
  #pragma unroll
  for (int li = 0; li < 8; ++li) GLOAD16(gsrc[li] + BK, (char*)lds + 32768 + ldsoff[li]);

  for (int t0 = 0; t0 < NT; ++t0) {
    if (t0 + 1 < NT) asm volatile("s_waitcnt vmcnt(8)" ::: "memory");
    else             asm volatile("s_waitcnt vmcnt(0)" ::: "memory");
    asm volatile("s_barrier" ::: "memory");
    __builtin_amdgcn_sched_barrier(0);

    const char* base = (const char*)lds + (t0 & 1) * 32768;
    bf16x8 af[2][4], bg[2][4];
    #pragma unroll
    for (int ks = 0; ks < 2; ++ks)
      #pragma unroll
      for (int f = 0; f < 4; ++f) {
        af[ks][f] = *(const bf16x8*)(base + aoff[ks][f]);
        bg[ks][f] = *(const bf16x8*)(base + boff[ks][f]);
      }
    asm volatile("s_waitcnt lgkmcnt(0)" ::: "memory");
    asm volatile("s_barrier" ::: "memory");
    __builtin_amdgcn_sched_barrier(0);

    if (t0 + 2 < NT) {
      #pragma unroll
      for (int li = 0; li < 8; ++li)
        GLOAD16(gsrc[li] + (t0 + 2) * BK, (char*)lds + (t0 & 1) * 32768 + ldsoff[li]);
    }

    __builtin_amdgcn_s_setprio(1);
    #pragma unroll
    for (int ks = 0; ks < 2; ++ks)
      #pragma unroll
      for (int mf = 0; mf < 4; ++mf)
        #pragma unroll
        for (int nf = 0; nf < 4; ++nf)
          acc[mf][nf] = __builtin_amdgcn_mfma_f32_16x16x32_bf16(af[ks][mf], bg[ks][nf], acc[mf][nf], 0, 0, 0);
    __builtin_amdgcn_s_setprio(0);
  }

  const int wm = wr * 64, wn = wc * 64;
  #pragma unroll
  for (int mf = 0; mf < 4; ++mf) {
    #pragma unroll
    for (int nf = 0; nf < 4; ++nf) {
      const int col = n0 + wn + nf * 16 + llo;
      if (mode == 1) {
        const int row_base = m0 + wm + mf * 16 + lhi * 4;
        const int bb = row_base >> 11, n = row_base & 2047;
        const int hh = col >> 6, dd = col & 63;
        short4v o;
        #pragma unroll
        for (int r = 0; r < 4; ++r) o[r] = (short)f2bf((acc[mf][nf][r] + bias[col]) * scale);
        unsigned short* p = (unsigned short*)Cv +
            ((size_t)((bb * NHEAD + hh) * HDIM + dd)) * NSEQ + n;
        *(short4v*)p = o;
      } else {
        #pragma unroll
        for (int r = 0; r < 4; ++r) {
          const int row = m0 + wm + mf * 16 + lhi * 4 + r;
          const float v = (acc[mf][nf][r] + bias[col]) * scale;
          if (mode == 0) {
            const int bb = row >> 11, n = row & 2047;
            const int hh = col >> 6, dd = col & 63;
            ((unsigned short*)Cv)[((size_t)(bb * NHEAD + hh) * NSEQ + n) * HDIM + dd] = f2bf(v);
          } else {
            ((float*)Cv)[(size_t)row * EMB + col] = v;
          }
        }
      }
    }
  }
}

__global__ __launch_bounds__(256, 2) void gemm_qkv(
    const unsigned short* __restrict__ A,
    const unsigned short* __restrict__ W0, const unsigned short* __restrict__ W1,
    const unsigned short* __restrict__ W2,
    const float* __restrict__ b0, const float* __restrict__ b1, const float* __restrict__ b2,
    unsigned short* __restrict__ O0, unsigned short* __restrict__ O1,
    unsigned short* __restrict__ O2) {
  const int m0 = blockIdx.x * 128, n0 = blockIdx.y * 128;
  const unsigned short* W = (blockIdx.z == 0) ? W0 : (blockIdx.z == 1) ? W1 : W2;
  const float* bb         = (blockIdx.z == 0) ? b0 : (blockIdx.z == 1) ? b1 : b2;
  unsigned short* O       = (blockIdx.z == 0) ? O0 : (blockIdx.z == 1) ? O1 : O2;
  const int mode          = (blockIdx.z == 2) ? 1 : 0;
  const float scale       = (blockIdx.z == 0) ? 0.03125f : 1.0f;  // fold 1/sqrt(EMB) into Q
  gemm_pipe(A, W, bb, (void*)O, m0, n0, mode, scale);
}

__global__ __launch_bounds__(256, 2) void gemm_proj(
    const unsigned short* __restrict__ A, const unsigned short* __restrict__ W,
    const float* __restrict__ bias, float* __restrict__ O) {
  gemm_pipe(A, W, bias, (void*)O, blockIdx.x * 128, blockIdx.y * 128, 2, 1.0f);
}

// ---------------- windowed flash attention, 64-key LDS-staged pipeline ----------------
// (r11-verified: 5 chunks of 64 keys, double-buffered LDS, counted vmcnt(4),
// 2 barriers/chunk, GEMM-proven swizzles, fixed-max softmax, ones-MFMA rowsum.)
__global__ __launch_bounds__(256, 4) void attn_kernel(
    const unsigned short* __restrict__ Qh, const unsigned short* __restrict__ Kh,
    const unsigned short* __restrict__ Vt, unsigned short* __restrict__ AO) {
  constexpr int NCH = 5;
  __shared__ char kv[2][16384];              // [slot][K 8KB | V 8KB]
  __shared__ unsigned short Pb[4][1024];     // per-wave 16x64 P (swizzled), 8KB
  const int t = threadIdx.x;
  const int lane = t & 63, wv = t >> 6;
  const int lhi = lane >> 4, llo = lane & 15;

  const int linear = blockIdx.x + 32 * (blockIdx.y + 16 * blockIdx.z);
  const int xcd = linear & 7, pos = linear >> 3;
  const int plane = xcd * 4 + (pos >> 5);
  const int qblk = pos & 31;
  const int b = plane >> 4, h = plane & 15;
  const int q0b = qblk * 64;
  const int q0 = q0b + wv * 16;

  const size_t pbase = (size_t)plane * NSEQ * HDIM;

  bf16x8 aq0, aq1;
  {
    const unsigned short* qp = Qh + pbase + (size_t)(q0 + llo) * HDIM + 8 * lhi;
    aq0 = *(const bf16x8*)qp;
    aq1 = *(const bf16x8*)(qp + 32);
  }

  int srow[4], scol8[4];
  #pragma unroll
  for (int li = 0; li < 4; ++li) {
    const int P = (li & 1) * 4096 + t * 16;
    const int L = P ^ (((P >> 7) & 7) << 4);
    srow[li] = L >> 7;
    scol8[li] = ((L >> 4) & 7) * 8;
  }

  int koff[4];
  #pragma unroll
  for (int half = 0; half < 4; ++half) {
    const int row = half * 16 + llo;
    koff[half] = (row * 128 + lhi * 16) ^ ((row & 7) << 4);
  }
  int voff[4][2];
  #pragma unroll
  for (int fd = 0; fd < 4; ++fd) {
    const int row = fd * 16 + llo;
    #pragma unroll
    for (int ks = 0; ks < 2; ++ks)
      voff[fd][ks] = 8192 + ((row * 128 + ks * 64 + lhi * 16) ^ ((row & 7) << 4));
  }
  int paoff[2];
  #pragma unroll
  for (int ks = 0; ks < 2; ++ks)
    paoff[ks] = (llo * 128 + ks * 64 + lhi * 16) ^ ((llo & 7) << 4);
  char* pb = (char*)&Pb[wv][0];

  bf16x8 vones;
  #pragma unroll
  for (int j = 0; j < 8; ++j) vones[j] = (short)0x3F80;   // bf16 1.0

  const f32x4 zero = {0.f, 0.f, 0.f, 0.f};
  f32x4 accv[4];
  f32x4 s_acc = zero;
  #pragma unroll
  for (int i = 0; i < 4; ++i) accv[i] = zero;

  auto stage = [&](int ct, int slot) {
    const int kb = q0b - WINDOW + ct * 64;
    #pragma unroll
    for (int li = 0; li < 2; ++li) {
      int n = kb + srow[li];
      n = n < 0 ? 0 : (n > NSEQ - 1 ? NSEQ - 1 : n);
      GLOAD16(Kh + pbase + (size_t)n * HDIM + scol8[li],
              (char*)kv[slot] + (li & 1) * 4096 + t * 16);
    }
    #pragma unroll
    for (int li = 2; li < 4; ++li) {
      int c = kb + scol8[li];
      c = c < 0 ? 0 : (c > NSEQ - 8 ? NSEQ - 8 : c);
      GLOAD16(Vt + pbase + (size_t)srow[li] * NSEQ + c,
              (char*)kv[slot] + 8192 + (li & 1) * 4096 + t * 16);
    }
  };

  stage(0, 0);
  stage(1, 1);

  for (int ct = 0; ct < NCH; ++ct) {
    if (ct + 1 < NCH) asm volatile("s_waitcnt vmcnt(4)" ::: "memory");
    else              asm volatile("s_waitcnt vmcnt(0)" ::: "memory");
    asm volatile("s_barrier" ::: "memory");
    __builtin_amdgcn_sched_barrier(0);

    const char* sb = kv[ct & 1];
    const int kb = q0b - WINDOW + ct * 64;

    // QK^T: 4 halves x 2 k-slices
    f32x4 e[4];
    #pragma unroll
    for (int half = 0; half < 4; ++half) {
      bf16x8 k0 = *(const bf16x8*)(sb + koff[half]);
      bf16x8 k1 = *(const bf16x8*)(sb + (koff[half] ^ 64));
      f32x4 z = zero;
      z = __builtin_amdgcn_mfma_f32_16x16x32_bf16(aq0, k0, z, 0, 0, 0);
      z = __builtin_amdgcn_mfma_f32_16x16x32_bf16(aq1, k1, z, 0, 0, 0);
      e[half] = z;
    }

    // mask + exp, write P (swizzled), e dies here
    #pragma unroll
    for (int half = 0; half < 4; ++half) {
      const int key = kb + half * 16 + llo;
      #pragma unroll
      for (int r = 0; r < 4; ++r) {
        const int q = q0 + lhi * 4 + r;
        const int dlt = key - q;
        const bool valid = (key >= 0) && (key < NSEQ) && (dlt <= WINDOW) && (dlt >= -WINDOW);
        const float p = __expf(valid ? fminf(e[half][r], 40.f) : -1e30f);
        const int row = lhi * 4 + r, col = half * 16 + llo;
        *(unsigned short*)(pb + ((row * 128 + col * 2) ^ ((row & 7) << 4))) = f2bf(p);
      }
    }
    const bf16x8 pa0 = *(const bf16x8*)(pb + paoff[0]);
    const bf16x8 pa1 = *(const bf16x8*)(pb + paoff[1]);

    // V fragments (after softmax: e[] dead before bv[] live -> lower VGPR peak)
    bf16x8 bv[4][2];
    #pragma unroll
    for (int fd = 0; fd < 4; ++fd) {
      bv[fd][0] = *(const bf16x8*)(sb + voff[fd][0]);
      bv[fd][1] = *(const bf16x8*)(sb + voff[fd][1]);
    }
    asm volatile("s_waitcnt lgkmcnt(0)" ::: "memory"); // all my slot reads retired
    __builtin_amdgcn_sched_barrier(0);
    asm volatile("s_barrier" ::: "memory");            // all waves done with slot
    __builtin_amdgcn_sched_barrier(0);

    if (ct + 2 < NCH) stage(ct + 2, ct & 1);           // restage freed slot

    __builtin_amdgcn_s_setprio(1);
    s_acc = __builtin_amdgcn_mfma_f32_16x16x32_bf16(pa0, vones, s_acc, 0, 0, 0);
    s_acc = __builtin_amdgcn_mfma_f32_16x16x32_bf16(pa1, vones, s_acc, 0, 0, 0);
    #pragma unroll
    for (int fd = 0; fd < 4; ++fd) {
      accv[fd] = __builtin_amdgcn_mfma_f32_16x16x32_bf16(pa0, bv[fd][0], accv[fd], 0, 0, 0);
      accv[fd] = __builtin_amdgcn_mfma_f32_16x16x32_bf16(pa1, bv[fd][1], accv[fd], 0, 0, 0);
    }
    __builtin_amdgcn_s_setprio(0);
  }

  #pragma unroll
  for (int fd = 0; fd < 4; ++fd) {
    #pragma unroll
    for (int r = 0; r < 4; ++r) {
      const float o = accv[fd][r] / s_acc[r];
      const int q = q0 + lhi * 4 + r;
      AO[((size_t)b * NSEQ + q) * EMB + h * HDIM + fd * 16 + llo] = f2bf(o);
    }
  }
}

// ---------------- launcher ----------------
extern "C" void kernel_launch(void* const* d_in, const int* in_sizes, int n_in,
                              void* d_out, int out_size, void* d_ws, size_t ws_size,
                              hipStream_t stream) {
  (void)in_sizes; (void)n_in; (void)out_size; (void)ws_size;
  const float* x  = (const float*)d_in[0];
  const float* Wq = (const float*)d_in[1];
  const float* bq = (const float*)d_in[2];
  const float* Wk = (const float*)d_in[3];
  const float* bk = (const float*)d_in[4];
  const float* Wv = (const float*)d_in[5];
  const float* bv = (const float*)d_in[6];
  const float* Wp = (const float*)d_in[7];
  const float* bp = (const float*)d_in[8];
  float* out = (float*)d_out;
  char* ws = (char*)d_ws;
  const size_t MB = 1u << 20;
  unsigned short* xb  = (unsigned short*)(ws + 0 * MB);
  unsigned short* Wqb = (unsigned short*)(ws + 8 * MB);
  unsigned short* Wkb = (unsigned short*)(ws + 10 * MB);
  unsigned short* Wvb = (unsigned short*)(ws + 12 * MB);
  unsigned short* Wpb = (unsigned short*)(ws + 14 * MB);
  unsigned short* Qb  = (unsigned short*)(ws + 16 * MB);
  unsigned short* Kb  = (unsigned short*)(ws + 24 * MB);
  unsigned short* Vtb = (unsigned short*)(ws + 32 * MB);
  unsigned short* AOb = (unsigned short*)(ws + 40 * MB);

  cvt_all<<<dim3(8192), dim3(256), 0, stream>>>(x, Wq, Wk, Wv, Wp,
                                                xb, Wqb, Wkb, Wvb, Wpb);

  gemm_qkv<<<dim3(MROWS / 128, EMB / 128, 3), dim3(256), 0, stream>>>(
      xb, Wqb, Wkb, Wvb, bq, bk, bv, Qb, Kb, Vtb);

  attn_kernel<<<dim3(NSEQ / 64, NHEAD, NBATCH), dim3(256), 0, stream>>>(Qb, Kb, Vtb, AOb);

  gemm_proj<<<dim3(MROWS / 128, EMB / 128), dim3(256), 0, stream>>>(AOb, Wpb, bp, out);
}